// Round 6
// baseline (1839.917 us; speedup 1.0000x reference)
//
#include <hip/hip_runtime.h>
#include <hip/hip_bf16.h>
#include <stdint.h>

#define T_STEPS 512
#define BATCH   128
#define IN      512
#define HID     1024
#define OUTN    256

typedef __bf16 bf16x8 __attribute__((ext_vector_type(8)));
typedef float  f32x4  __attribute__((ext_vector_type(4)));
typedef unsigned short us8 __attribute__((ext_vector_type(8)));
typedef unsigned int   ui4 __attribute__((ext_vector_type(4)));

#define TAGM 0x80008000u
#define CLRM 0x7FFF7FFFu

__device__ __forceinline__ unsigned short f2bf(float f) {
    uint32_t u = __float_as_uint(f);
    uint32_t r = (u + 0x7fffu + ((u >> 16) & 1u)) >> 16;   // RNE
    return (unsigned short)r;
}

// Agent-coherent 16B load (bypass L1+L2, read at LLC). Issue-only; completion
// claimed by explicit counted s_waitcnt.
__device__ __forceinline__ ui4 ld_u128_agent(const void* p) {
    ui4 v;
    asm volatile("global_load_dwordx4 %0, %1, off sc0 sc1"
                 : "=v"(v) : "v"(p) : "memory");
    return v;
}

// Swizzled LDS fragment load: 16B at row*stride + (kbyte ^ ((row&7)<<4))
__device__ __forceinline__ bf16x8 ld_frag(const unsigned short* smem, int row, int kbyte, int rowstride) {
    int off = row * rowstride + (kbyte ^ ((row & 7) << 4));
    return *reinterpret_cast<const bf16x8*>(reinterpret_cast<const char*>(smem) + off);
}
__device__ __forceinline__ us8 ld_frag_u(const unsigned short* smem, int row, int kbyte, int rowstride) {
    int off = row * rowstride + (kbyte ^ ((row & 7) << 4));
    return *reinterpret_cast<const us8*>(reinterpret_cast<const char*>(smem) + off);
}

__global__ __launch_bounds__(512, 1) void rnn_persistent(
    const float* __restrict__ seqs, const float* __restrict__ W_ih,
    const float* __restrict__ W_hh, const float* __restrict__ b_ih,
    const float* __restrict__ b_hh, const float* __restrict__ W_fc,
    const float* __restrict__ b_fc, float* __restrict__ out,
    unsigned short* __restrict__ hbuf,   // [2][128][1024] bf16 ring, zeroed each call
    unsigned int* __restrict__ flags)    // [8][16] steps-completed per WG, zeroed
{
    const int tid   = threadIdx.x;
    const int lane  = tid & 63;
    const int wv    = tid >> 6;          // wave 0..7
    const int kteam = wv & 3;            // K-split 0..3
    const int chalf = wv >> 2;           // col half 0..1 (32 cols each)
    const int wg    = blockIdx.x;
    const int g     = wg >> 4;           // batch group 0..7 (rows g*16..+15)
    const int w     = wg & 15;           // col slice (cols w*64..+63)
    const int gr0   = g * 16;
    const int c0    = w * 64;
    const int ln15  = lane & 15;
    const int lk    = lane >> 4;

    __shared__ unsigned short xtile[16 * 512];   // 16KB, swizzled bf16
    __shared__ unsigned short htile[16 * 1024];  // 32KB, swizzled bf16
    __shared__ float red[4][16][66];             // K-team partials (16.5KB)
    __shared__ float biasS[64];

    // ---- init: weight B-fragments into registers (bf16) ----
    bf16x8 wih[2][4];
    bf16x8 whh[2][8];
    #pragma unroll
    for (int nt = 0; nt < 2; nt++) {
        const int j = c0 + chalf * 32 + nt * 16 + ln15;
        #pragma unroll
        for (int s = 0; s < 4; s++) {
            const int k = kteam * 128 + s * 32 + lk * 8;
            const float* p = W_ih + j * IN + k;
            us8 u;
            #pragma unroll
            for (int e = 0; e < 8; e++) u[e] = f2bf(p[e]);
            wih[nt][s] = __builtin_bit_cast(bf16x8, u);
        }
        #pragma unroll
        for (int s = 0; s < 8; s++) {
            const int k = kteam * 256 + s * 32 + lk * 8;
            const float* p = W_hh + j * HID + k;
            us8 u;
            #pragma unroll
            for (int e = 0; e < 8; e++) u[e] = f2bf(p[e]);
            whh[nt][s] = __builtin_bit_cast(bf16x8, u);
        }
    }
    if (tid < 64) biasS[tid] = b_ih[c0 + tid] + b_hh[c0 + tid];

    unsigned int* grp_flags = flags + g * 16;
    unsigned int* my_flag   = grp_flags + w;

    // per-thread h chunk offsets (16B chunks; 16 rows x 128 chunks / 512 thr = 4)
    int hgoff[4], hloff[4];
    #pragma unroll
    for (int it = 0; it < 4; it++) {
        const int c    = tid + it * 512;
        const int row  = c >> 7;
        const int colc = c & 127;
        hgoff[it] = row * 2048 + colc * 16;
        hloff[it] = row * 2048 + ((colc * 16) ^ ((row & 7) << 4));
    }

    // per-thread x chunk coords (16B chunks; 16 rows x 64 chunks / 512 thr = 2)
    const int xrow[2] = { (tid) >> 6, (tid + 512) >> 6 };
    const int xcol[2] = { (tid) & 63, (tid + 512) & 63 };

    // ---- prologue: load + convert x(0) ----
    us8 xbf[2];
    {
        const float* xsrc = seqs + (size_t)gr0 * IN;
        #pragma unroll
        for (int it = 0; it < 2; it++) {
            const float* s4 = xsrc + xrow[it] * IN + xcol[it] * 8;
            float4 a = *reinterpret_cast<const float4*>(s4);
            float4 b = *reinterpret_cast<const float4*>(s4 + 4);
            us8 u;
            u[0]=f2bf(a.x); u[1]=f2bf(a.y); u[2]=f2bf(a.z); u[3]=f2bf(a.w);
            u[4]=f2bf(b.x); u[5]=f2bf(b.y); u[6]=f2bf(b.z); u[7]=f2bf(b.w);
            xbf[it] = u;
        }
    }

    const size_t slotB = (size_t)BATCH * HID * 2;   // 256KB per ring slot
    char* hbase = reinterpret_cast<char*>(hbuf);

    for (int t = 0; t < T_STEPS; t++) {
        // 1: SPECULATIVE h(t) read — issued before the spin, overlapped with it.
        ui4 hv[4];
        const char* hsrc = hbase + (size_t)(t & 1) * slotB + (size_t)gr0 * HID * 2;
        if (t > 0) {
            #pragma unroll
            for (int it = 0; it < 4; it++) hv[it] = ld_u128_agent(hsrc + hgoff[it]);
        }
        __builtin_amdgcn_sched_barrier(0);

        // 2: write prepared x(t) -> xtile (LDS, swizzled)
        #pragma unroll
        for (int it = 0; it < 2; it++) {
            const int off = xrow[it] * 1024 + ((xcol[it] * 16) ^ ((xrow[it] & 7) << 4));
            *reinterpret_cast<us8*>(reinterpret_cast<char*>(xtile) + off) = xbf[it];
        }

        // 3: issue x(t+1) plain loads (stay in flight across vmcnt(4))
        float4 xr[4];
        {
            const int tn = (t + 1 < T_STEPS) ? t + 1 : t;
            const float* xsrc = seqs + (size_t)tn * (BATCH * IN) + (size_t)gr0 * IN;
            #pragma unroll
            for (int it = 0; it < 2; it++) {
                const float* s4 = xsrc + xrow[it] * IN + xcol[it] * 8;
                xr[2*it]   = *reinterpret_cast<const float4*>(s4);
                xr[2*it+1] = *reinterpret_cast<const float4*>(s4 + 4);
            }
        }
        __builtin_amdgcn_sched_barrier(0);

        // 4: flag spin (wave0, 16 lanes, no sleep) — authoritative readiness
        if (t > 0 && wv == 0 && lane < 16) {
            const unsigned int* f = grp_flags + lane;
            while (__hip_atomic_load(f, __ATOMIC_RELAXED, __HIP_MEMORY_SCOPE_AGENT) < (unsigned)t) { }
        }
        __syncthreads();   // xtile visible; h(t) globally complete

        // 5: x-projection MFMAs
        f32x4 acc0 = {0.f, 0.f, 0.f, 0.f};
        f32x4 acc1 = {0.f, 0.f, 0.f, 0.f};
        {
            const int kx0b = kteam * 256;
            #pragma unroll
            for (int s = 0; s < 4; s++) {
                bf16x8 a = ld_frag(xtile, ln15, kx0b + s * 64 + lk * 16, 1024);
                acc0 = __builtin_amdgcn_mfma_f32_16x16x32_bf16(a, wih[0][s], acc0, 0, 0, 0);
                acc1 = __builtin_amdgcn_mfma_f32_16x16x32_bf16(a, wih[1][s], acc1, 0, 0, 0);
            }
        }

        if (t > 0) {
            // 6: claim the 4 oldest (spec h); tag-check; bounded re-read (flag => fresh)
            const unsigned pr = ((t >> 1) & 1) ? 0x80000000u : 0x00008000u;
            asm volatile("s_waitcnt vmcnt(4)" ::: "memory");
            __builtin_amdgcn_sched_barrier(0);
            unsigned pending = 0xFu;
            while (true) {
                unsigned np = 0;
                #pragma unroll
                for (int it = 0; it < 4; it++) {
                    if (pending & (1u << it)) {
                        unsigned d = ((hv[it][0] & TAGM) ^ pr) | ((hv[it][1] & TAGM) ^ pr)
                                   | ((hv[it][2] & TAGM) ^ pr) | ((hv[it][3] & TAGM) ^ pr);
                        if (d != 0u) {
                            np |= (1u << it);
                            hv[it] = ld_u128_agent(hsrc + hgoff[it]);
                        }
                    }
                }
                pending = np;
                if (pending == 0u) break;
                asm volatile("s_waitcnt vmcnt(0)" ::: "memory");   // at most one extra round
                __builtin_amdgcn_sched_barrier(0);
            }
            // strip epoch tags, stage htile (swizzled)
            #pragma unroll
            for (int it = 0; it < 4; it++) {
                ui4 v = hv[it];
                v[0] &= CLRM; v[1] &= CLRM; v[2] &= CLRM; v[3] &= CLRM;
                *reinterpret_cast<ui4*>(reinterpret_cast<char*>(htile) + hloff[it]) = v;
            }
            __syncthreads();

            // 7: recurrence MFMAs
            const int kh0b = kteam * 512;
            #pragma unroll
            for (int s = 0; s < 8; s++) {
                bf16x8 a = ld_frag(htile, ln15, kh0b + s * 64 + lk * 16, 2048);
                acc0 = __builtin_amdgcn_mfma_f32_16x16x32_bf16(a, whh[0][s], acc0, 0, 0, 0);
                acc1 = __builtin_amdgcn_mfma_f32_16x16x32_bf16(a, whh[1][s], acc1, 0, 0, 0);
            }
        }

        // 8: K-team reduction partials
        #pragma unroll
        for (int r = 0; r < 4; r++) {
            red[kteam][lk * 4 + r][chalf * 32 + ln15]      = acc0[r];
            red[kteam][lk * 4 + r][chalf * 32 + 16 + ln15] = acc1[r];
        }
        __syncthreads();
        {
            const int hrow = tid >> 5;          // 0..15
            const int co2  = (tid & 31) * 2;    // 0..62 within 64-col slice
            float v0 = red[0][hrow][co2]   + red[1][hrow][co2]   + red[2][hrow][co2]   + red[3][hrow][co2]   + biasS[co2];
            float v1 = red[0][hrow][co2+1] + red[1][hrow][co2+1] + red[2][hrow][co2+1] + red[3][hrow][co2+1] + biasS[co2+1];
            v0 = fmaxf(v0, 0.0f);
            v1 = fmaxf(v1, 0.0f);

            // 9: store epoch-tagged H_{t+1} (always to ring; FC reads ring)
            const unsigned pw = (((t + 1) >> 1) & 1) ? 0x80000000u : 0x00008000u;
            unsigned pack = (unsigned)f2bf(v0) | ((unsigned)f2bf(v1) << 16) | pw;
            unsigned* dst = reinterpret_cast<unsigned*>(
                hbase + (size_t)((t + 1) & 1) * slotB
                + ((size_t)(gr0 + hrow) * HID + c0 + co2) * 2);
            __hip_atomic_store(dst, pack, __ATOMIC_RELAXED, __HIP_MEMORY_SCOPE_AGENT);
        }
        asm volatile("s_waitcnt vmcnt(0)" ::: "memory");  // h stores acked (also claims x)
        __builtin_amdgcn_sched_barrier(0);
        __syncthreads();                                   // every thread drained
        if (tid == 0) {
            __hip_atomic_store(my_flag, (unsigned)(t + 1), __ATOMIC_RELAXED, __HIP_MEMORY_SCOPE_AGENT);
        }

        // 10: convert x(t+1) — off the peer-observation critical path
        #pragma unroll
        for (int it = 0; it < 2; it++) {
            float4 a = xr[2*it], b = xr[2*it+1];
            us8 u;
            u[0]=f2bf(a.x); u[1]=f2bf(a.y); u[2]=f2bf(a.z); u[3]=f2bf(a.w);
            u[4]=f2bf(b.x); u[5]=f2bf(b.y); u[6]=f2bf(b.z); u[7]=f2bf(b.w);
            xbf[it] = u;
        }
    }

    // ---- FC epilogue: H_512 in ring slot 0, tag 0x00008000 ----
    {
        const char* hsrc = hbase + (size_t)gr0 * HID * 2;
        ui4 hv[4];
        #pragma unroll
        for (int it = 0; it < 4; it++) hv[it] = ld_u128_agent(hsrc + hgoff[it]);
        __builtin_amdgcn_sched_barrier(0);
        if (wv == 0 && lane < 16) {
            const unsigned int* f = grp_flags + lane;
            while (__hip_atomic_load(f, __ATOMIC_RELAXED, __HIP_MEMORY_SCOPE_AGENT) < (unsigned)T_STEPS) { }
        }
        __syncthreads();
        asm volatile("s_waitcnt vmcnt(0)" ::: "memory");
        __builtin_amdgcn_sched_barrier(0);
        unsigned pending = 0xFu;
        while (true) {
            unsigned np = 0;
            #pragma unroll
            for (int it = 0; it < 4; it++) {
                if (pending & (1u << it)) {
                    unsigned d = ((hv[it][0] & TAGM) ^ 0x00008000u) | ((hv[it][1] & TAGM) ^ 0x00008000u)
                               | ((hv[it][2] & TAGM) ^ 0x00008000u) | ((hv[it][3] & TAGM) ^ 0x00008000u);
                    if (d != 0u) {
                        np |= (1u << it);
                        hv[it] = ld_u128_agent(hsrc + hgoff[it]);
                    }
                }
            }
            pending = np;
            if (pending == 0u) break;
            asm volatile("s_waitcnt vmcnt(0)" ::: "memory");
            __builtin_amdgcn_sched_barrier(0);
        }
        #pragma unroll
        for (int it = 0; it < 4; it++) {
            ui4 v = hv[it];
            v[0] &= CLRM; v[1] &= CLRM; v[2] &= CLRM; v[3] &= CLRM;
            *reinterpret_cast<ui4*>(reinterpret_cast<char*>(htile) + hloff[it]) = v;
        }
        __syncthreads();
    }

    // out[gr0+row][w*16+oc] = sum_k htile[row][k]*W_fc[o][k] + b_fc[o]; 2-way K-split
    {
        const int oi   = tid & 255;
        const int half = tid >> 8;
        const int row  = oi >> 4;
        const int o    = w * 16 + (oi & 15);
        const float* wf = W_fc + (size_t)o * HID + half * 512;
        float sum = 0.f;
        #pragma unroll 4
        for (int ck = 0; ck < 64; ck++) {
            us8 hu = ld_frag_u(htile, row, half * 1024 + ck * 16, 2048);
            float4 wa = *reinterpret_cast<const float4*>(wf + ck * 8);
            float4 wb = *reinterpret_cast<const float4*>(wf + ck * 8 + 4);
            sum += __uint_as_float((unsigned)hu[0] << 16) * wa.x
                 + __uint_as_float((unsigned)hu[1] << 16) * wa.y
                 + __uint_as_float((unsigned)hu[2] << 16) * wa.z
                 + __uint_as_float((unsigned)hu[3] << 16) * wa.w
                 + __uint_as_float((unsigned)hu[4] << 16) * wb.x
                 + __uint_as_float((unsigned)hu[5] << 16) * wb.y
                 + __uint_as_float((unsigned)hu[6] << 16) * wb.z
                 + __uint_as_float((unsigned)hu[7] << 16) * wb.w;
        }
        float* redf = &red[0][0][0];
        redf[tid] = sum;
        __syncthreads();
        if (tid < 256) {
            out[(size_t)(gr0 + (tid >> 4)) * OUTN + w * 16 + (tid & 15)] =
                redf[tid] + redf[tid + 256] + b_fc[w * 16 + (tid & 15)];
        }
    }
}

extern "C" void kernel_launch(void* const* d_in, const int* in_sizes, int n_in,
                              void* d_out, int out_size, void* d_ws, size_t ws_size,
                              hipStream_t stream) {
    const float* seqs = (const float*)d_in[0];
    const float* W_ih = (const float*)d_in[1];
    const float* W_hh = (const float*)d_in[2];
    const float* b_ih = (const float*)d_in[3];
    const float* b_hh = (const float*)d_in[4];
    const float* W_fc = (const float*)d_in[5];
    const float* b_fc = (const float*)d_in[6];
    float* out = (float*)d_out;

    char* ws = (char*)d_ws;
    unsigned short* hbuf  = (unsigned short*)ws;            // 2*128*1024*2 = 524288 B ring
    unsigned int*   flags = (unsigned int*)(ws + 524288);   // 8*16*4 = 512 B

    // Zero ring (epoch tags {1,2} never match 0) + flags, every call.
    hipMemsetAsync(ws, 0, 524288 + 512, stream);
    rnn_persistent<<<dim3(128), dim3(512), 0, stream>>>(
        seqs, W_ih, W_hh, b_ih, b_hh, W_fc, b_fc, out, hbuf, flags);
}

// Round 7
// 1566.039 us; speedup vs baseline: 1.1749x; 1.1749x over previous
//
#include <hip/hip_runtime.h>
#include <hip/hip_bf16.h>
#include <stdint.h>

#define T_STEPS 512
#define BATCH   128
#define IN      512
#define HID     1024
#define OUTN    256

typedef __bf16 bf16x8 __attribute__((ext_vector_type(8)));
typedef float  f32x4  __attribute__((ext_vector_type(4)));
typedef unsigned short us8 __attribute__((ext_vector_type(8)));
typedef unsigned int   ui4 __attribute__((ext_vector_type(4)));

#define TAGM 0x80008000u
#define CLRM 0x7FFF7FFFu

__device__ __forceinline__ unsigned short f2bf(float f) {
    uint32_t u = __float_as_uint(f);
    uint32_t r = (u + 0x7fffu + ((u >> 16) & 1u)) >> 16;   // RNE
    return (unsigned short)r;
}

// Agent-coherent 16B load (bypass L1+L2, read at LLC). Issue-only; completion
// claimed by explicit s_waitcnt.
__device__ __forceinline__ ui4 ld_u128_agent(const void* p) {
    ui4 v;
    asm volatile("global_load_dwordx4 %0, %1, off sc0 sc1"
                 : "=v"(v) : "v"(p) : "memory");
    return v;
}

// Swizzled LDS fragment load: 16B at row*stride + (kbyte ^ ((row&7)<<4))
__device__ __forceinline__ bf16x8 ld_frag(const unsigned short* smem, int row, int kbyte, int rowstride) {
    int off = row * rowstride + (kbyte ^ ((row & 7) << 4));
    return *reinterpret_cast<const bf16x8*>(reinterpret_cast<const char*>(smem) + off);
}
__device__ __forceinline__ us8 ld_frag_u(const unsigned short* smem, int row, int kbyte, int rowstride) {
    int off = row * rowstride + (kbyte ^ ((row & 7) << 4));
    return *reinterpret_cast<const us8*>(reinterpret_cast<const char*>(smem) + off);
}

__global__ __launch_bounds__(256, 1) void rnn_persistent(
    const float* __restrict__ seqs, const float* __restrict__ W_ih,
    const float* __restrict__ W_hh, const float* __restrict__ b_ih,
    const float* __restrict__ b_hh, const float* __restrict__ W_fc,
    const float* __restrict__ b_fc, float* __restrict__ out,
    unsigned short* __restrict__ hbuf,   // [2][128][1024] bf16 ring (epoch-tagged), zeroed
    unsigned int* __restrict__ flags)    // [8][32] steps-completed per WG, zeroed
{
    const int tid  = threadIdx.x;
    const int lane = tid & 63;
    const int wv   = tid >> 6;          // wave 0..3 (K-split)
    const int wg   = blockIdx.x;
    const int g    = wg >> 5;           // batch group 0..7 (rows g*16..+15)
    const int w    = wg & 31;           // col slice (cols w*32..+31)
    const int gr0  = g * 16;
    const int c0   = w * 32;
    const int ln15 = lane & 15;
    const int lk   = lane >> 4;

    __shared__ unsigned short xtile[16 * 512];   // 16KB, swizzled bf16
    __shared__ unsigned short htile[16 * 1024];  // 32KB, swizzled bf16
    __shared__ float red[4][16][33];             // wave partials (+1 pad)
    __shared__ float biasS[32];

    // ---- init: weight B-fragments into registers (bf16) ----
    bf16x8 wih[2][4];
    bf16x8 whh[2][8];
    #pragma unroll
    for (int nt = 0; nt < 2; nt++) {
        const int j = c0 + nt * 16 + ln15;
        #pragma unroll
        for (int s = 0; s < 4; s++) {
            const int k = wv * 128 + s * 32 + lk * 8;
            const float* p = W_ih + j * IN + k;
            us8 u;
            #pragma unroll
            for (int e = 0; e < 8; e++) u[e] = f2bf(p[e]);
            wih[nt][s] = __builtin_bit_cast(bf16x8, u);
        }
        #pragma unroll
        for (int s = 0; s < 8; s++) {
            const int k = wv * 256 + s * 32 + lk * 8;
            const float* p = W_hh + j * HID + k;
            us8 u;
            #pragma unroll
            for (int e = 0; e < 8; e++) u[e] = f2bf(p[e]);
            whh[nt][s] = __builtin_bit_cast(bf16x8, u);
        }
    }
    if (tid < 32) biasS[tid] = b_ih[c0 + tid] + b_hh[c0 + tid];

    unsigned int* grp_flags = flags + g * 32;
    unsigned int* my_flag   = grp_flags + w;

    // per-thread h chunk offsets (16B chunks, 128 per row of [16][1024])
    int hgoff[8], hloff[8];
    #pragma unroll
    for (int it = 0; it < 8; it++) {
        const int c    = tid + it * 256;
        const int row  = c >> 7;
        const int colc = c & 127;
        hgoff[it] = row * 2048 + colc * 16;
        hloff[it] = row * 2048 + ((colc * 16) ^ ((row & 7) << 4));
    }

    // per-thread x chunk coords (16B chunks, 64 per row)
    const int xrow[4] = { (tid) >> 6, (tid + 256) >> 6, (tid + 512) >> 6, (tid + 768) >> 6 };
    const int xcol[4] = { (tid) & 63, (tid + 256) & 63, (tid + 512) & 63, (tid + 768) & 63 };

    // ---- prologue: load + convert x(0) ----
    us8 xbf[4];
    {
        const float* xsrc = seqs + (size_t)gr0 * IN;
        #pragma unroll
        for (int it = 0; it < 4; it++) {
            const float* s4 = xsrc + xrow[it] * IN + xcol[it] * 8;
            float4 a = *reinterpret_cast<const float4*>(s4);
            float4 b = *reinterpret_cast<const float4*>(s4 + 4);
            us8 u;
            u[0]=f2bf(a.x); u[1]=f2bf(a.y); u[2]=f2bf(a.z); u[3]=f2bf(a.w);
            u[4]=f2bf(b.x); u[5]=f2bf(b.y); u[6]=f2bf(b.z); u[7]=f2bf(b.w);
            xbf[it] = u;
        }
    }

    const size_t slotB = (size_t)BATCH * HID * 2;   // 256KB per ring slot
    char* hbase = reinterpret_cast<char*>(hbuf);

    for (int t = 0; t < T_STEPS; t++) {
        // 1: write prepared x(t) -> xtile (swizzled)
        #pragma unroll
        for (int it = 0; it < 4; it++) {
            const int off = xrow[it] * 1024 + ((xcol[it] * 16) ^ ((xrow[it] & 7) << 4));
            *reinterpret_cast<us8*>(reinterpret_cast<char*>(xtile) + off) = xbf[it];
        }

        // 2: issue x(t+1) plain loads (HBM latency hides under the spin)
        float4 xr[8];
        {
            const int tn = (t + 1 < T_STEPS) ? t + 1 : t;
            const float* xsrc = seqs + (size_t)tn * (BATCH * IN) + (size_t)gr0 * IN;
            #pragma unroll
            for (int it = 0; it < 4; it++) {
                const float* s4 = xsrc + xrow[it] * IN + xcol[it] * 8;
                xr[2*it]   = *reinterpret_cast<const float4*>(s4);
                xr[2*it+1] = *reinterpret_cast<const float4*>(s4 + 4);
            }
        }

        // 3: flag spin — the WAIT primitive (cheap); tags below are the CERTIFICATE
        if (t > 0 && wv == 0 && lane < 32) {
            const unsigned int* f = grp_flags + lane;
            while (__hip_atomic_load(f, __ATOMIC_RELAXED, __HIP_MEMORY_SCOPE_AGENT) < (unsigned)t) { }
        }
        __syncthreads();   // B1: xtile visible; peers' flags >= t

        // 4: issue 8 agent h-loads
        ui4 hv[8];
        const char* hsrc = hbase + (size_t)(t & 1) * slotB + (size_t)gr0 * HID * 2;
        if (t > 0) {
            #pragma unroll
            for (int it = 0; it < 8; it++) hv[it] = ld_u128_agent(hsrc + hgoff[it]);
        }
        __builtin_amdgcn_sched_barrier(0);

        // 5: x-projection MFMAs (overlap h-load round trip)
        f32x4 acc0 = {0.f, 0.f, 0.f, 0.f};
        f32x4 acc1 = {0.f, 0.f, 0.f, 0.f};
        {
            const int kx0b = wv * 256;
            #pragma unroll
            for (int s = 0; s < 4; s++) {
                bf16x8 a = ld_frag(xtile, ln15, kx0b + s * 64 + lk * 16, 1024);
                acc0 = __builtin_amdgcn_mfma_f32_16x16x32_bf16(a, wih[0][s], acc0, 0, 0, 0);
                acc1 = __builtin_amdgcn_mfma_f32_16x16x32_bf16(a, wih[1][s], acc1, 0, 0, 0);
            }
        }

        if (t > 0) {
            // 6: claim loads; tag-certify; re-read any chunk whose writer's
            // stores hadn't landed yet (flag was stored WITHOUT a drain)
            const unsigned pr = ((t >> 1) & 1) ? 0x80000000u : 0x00008000u;
            asm volatile("s_waitcnt vmcnt(0)" ::: "memory");
            __builtin_amdgcn_sched_barrier(0);
            unsigned pending = 0xFFu;
            while (true) {
                unsigned np = 0;
                #pragma unroll
                for (int it = 0; it < 8; it++) {
                    if (pending & (1u << it)) {
                        unsigned d = ((hv[it][0] & TAGM) ^ pr) | ((hv[it][1] & TAGM) ^ pr)
                                   | ((hv[it][2] & TAGM) ^ pr) | ((hv[it][3] & TAGM) ^ pr);
                        if (d != 0u) {
                            np |= (1u << it);
                            hv[it] = ld_u128_agent(hsrc + hgoff[it]);
                        }
                    }
                }
                pending = np;
                if (pending == 0u) break;
                asm volatile("s_waitcnt vmcnt(0)" ::: "memory");   // rare extra round
                __builtin_amdgcn_sched_barrier(0);
            }
            // strip epoch tags, stage htile (swizzled)
            #pragma unroll
            for (int it = 0; it < 8; it++) {
                ui4 v = hv[it];
                v[0] &= CLRM; v[1] &= CLRM; v[2] &= CLRM; v[3] &= CLRM;
                *reinterpret_cast<ui4*>(reinterpret_cast<char*>(htile) + hloff[it]) = v;
            }
            __syncthreads();   // B2: htile staged (also: all waves claimed their reads)

            // 7: recurrence MFMAs
            const int kh0b = wv * 512;
            #pragma unroll
            for (int s = 0; s < 8; s++) {
                bf16x8 a = ld_frag(htile, ln15, kh0b + s * 64 + lk * 16, 2048);
                acc0 = __builtin_amdgcn_mfma_f32_16x16x32_bf16(a, whh[0][s], acc0, 0, 0, 0);
                acc1 = __builtin_amdgcn_mfma_f32_16x16x32_bf16(a, whh[1][s], acc1, 0, 0, 0);
            }
        }

        // 8: cross-wave K-reduction partials
        #pragma unroll
        for (int r = 0; r < 4; r++) {
            red[wv][lk * 4 + r][ln15]      = acc0[r];
            red[wv][lk * 4 + r][16 + ln15] = acc1[r];
        }
        __syncthreads();   // B3

        // 9: reduce + bias + relu
        const int hrow = tid >> 4;          // 0..15
        const int co2  = (tid & 15) * 2;    // even col within slice
        float v0 = red[0][hrow][co2]   + red[1][hrow][co2]   + red[2][hrow][co2]   + red[3][hrow][co2]   + biasS[co2];
        float v1 = red[0][hrow][co2+1] + red[1][hrow][co2+1] + red[2][hrow][co2+1] + red[3][hrow][co2+1] + biasS[co2+1];
        v0 = fmaxf(v0, 0.0f);
        v1 = fmaxf(v1, 0.0f);

        // 10: store epoch-tagged H_{t+1} — NO drain before the flag
        {
            const unsigned pw = (((t + 1) >> 1) & 1) ? 0x80000000u : 0x00008000u;
            unsigned pack = (unsigned)f2bf(v0) | ((unsigned)f2bf(v1) << 16) | pw;
            unsigned* dst = reinterpret_cast<unsigned*>(
                hbase + (size_t)((t + 1) & 1) * slotB
                + ((size_t)(gr0 + hrow) * HID + c0 + co2) * 2);
            __hip_atomic_store(dst, pack, __ATOMIC_RELAXED, __HIP_MEMORY_SCOPE_AGENT);
        }

        // 11: signal immediately (readers certify via tags)
        if (tid == 0) {
            __hip_atomic_store(my_flag, (unsigned)(t + 1), __ATOMIC_RELAXED, __HIP_MEMORY_SCOPE_AGENT);
        }

        // 12: claim x(t+1) and convert — off the signal path
        asm volatile("s_waitcnt vmcnt(0)" ::: "memory");
        __builtin_amdgcn_sched_barrier(0);
        #pragma unroll
        for (int it = 0; it < 4; it++) {
            float4 a = xr[2*it], b = xr[2*it+1];
            us8 u;
            u[0]=f2bf(a.x); u[1]=f2bf(a.y); u[2]=f2bf(a.z); u[3]=f2bf(a.w);
            u[4]=f2bf(b.x); u[5]=f2bf(b.y); u[6]=f2bf(b.z); u[7]=f2bf(b.w);
            xbf[it] = u;
        }
    }

    // ---- FC epilogue: H_512 in ring slot 0, gen-512 tag = 0x00008000 ----
    {
        if (wv == 0 && lane < 32) {
            const unsigned int* f = grp_flags + lane;
            while (__hip_atomic_load(f, __ATOMIC_RELAXED, __HIP_MEMORY_SCOPE_AGENT) < (unsigned)T_STEPS) { }
        }
        __syncthreads();
        const char* hsrc = hbase + (size_t)gr0 * HID * 2;
        ui4 hv[8];
        #pragma unroll
        for (int it = 0; it < 8; it++) hv[it] = ld_u128_agent(hsrc + hgoff[it]);
        asm volatile("s_waitcnt vmcnt(0)" ::: "memory");
        __builtin_amdgcn_sched_barrier(0);
        unsigned pending = 0xFFu;
        while (true) {
            unsigned np = 0;
            #pragma unroll
            for (int it = 0; it < 8; it++) {
                if (pending & (1u << it)) {
                    unsigned d = ((hv[it][0] & TAGM) ^ 0x00008000u) | ((hv[it][1] & TAGM) ^ 0x00008000u)
                               | ((hv[it][2] & TAGM) ^ 0x00008000u) | ((hv[it][3] & TAGM) ^ 0x00008000u);
                    if (d != 0u) {
                        np |= (1u << it);
                        hv[it] = ld_u128_agent(hsrc + hgoff[it]);
                    }
                }
            }
            pending = np;
            if (pending == 0u) break;
            asm volatile("s_waitcnt vmcnt(0)" ::: "memory");
            __builtin_amdgcn_sched_barrier(0);
        }
        #pragma unroll
        for (int it = 0; it < 8; it++) {
            ui4 v = hv[it];
            v[0] &= CLRM; v[1] &= CLRM; v[2] &= CLRM; v[3] &= CLRM;
            *reinterpret_cast<ui4*>(reinterpret_cast<char*>(htile) + hloff[it]) = v;
        }
        __syncthreads();
    }

    // out[gr0+row][w*8+oc] = sum_k htile[row][k]*W_fc[o][k] + b_fc[o]; 2-way K-split
    {
        const int oi   = tid & 127;
        const int half = tid >> 7;
        const int row  = oi >> 3;
        const int o    = w * 8 + (oi & 7);
        const float* wf = W_fc + (size_t)o * HID + half * 512;
        float sum = 0.f;
        #pragma unroll 4
        for (int ck = 0; ck < 64; ck++) {
            us8 hu = ld_frag_u(htile, row, half * 1024 + ck * 16, 2048);
            float4 wa = *reinterpret_cast<const float4*>(wf + ck * 8);
            float4 wb = *reinterpret_cast<const float4*>(wf + ck * 8 + 4);
            sum += __uint_as_float((unsigned)hu[0] << 16) * wa.x
                 + __uint_as_float((unsigned)hu[1] << 16) * wa.y
                 + __uint_as_float((unsigned)hu[2] << 16) * wa.z
                 + __uint_as_float((unsigned)hu[3] << 16) * wa.w
                 + __uint_as_float((unsigned)hu[4] << 16) * wb.x
                 + __uint_as_float((unsigned)hu[5] << 16) * wb.y
                 + __uint_as_float((unsigned)hu[6] << 16) * wb.z
                 + __uint_as_float((unsigned)hu[7] << 16) * wb.w;
        }
        float* redf = &red[0][0][0];
        redf[tid] = sum;
        __syncthreads();
        if (tid < 128) {
            out[(size_t)(gr0 + row) * OUTN + o] = redf[tid] + redf[tid + 128] + b_fc[o];
        }
    }
}

extern "C" void kernel_launch(void* const* d_in, const int* in_sizes, int n_in,
                              void* d_out, int out_size, void* d_ws, size_t ws_size,
                              hipStream_t stream) {
    const float* seqs = (const float*)d_in[0];
    const float* W_ih = (const float*)d_in[1];
    const float* W_hh = (const float*)d_in[2];
    const float* b_ih = (const float*)d_in[3];
    const float* b_hh = (const float*)d_in[4];
    const float* W_fc = (const float*)d_in[5];
    const float* b_fc = (const float*)d_in[6];
    float* out = (float*)d_out;

    char* ws = (char*)d_ws;
    unsigned short* hbuf  = (unsigned short*)ws;            // 2*128*1024*2 = 524288 B ring
    unsigned int*   flags = (unsigned int*)(ws + 524288);   // 8*32*4 = 1024 B

    // Zero ring (epoch tags {1,2} never match 0) + flags, every call.
    hipMemsetAsync(ws, 0, 524288 + 1024, stream);
    rnn_persistent<<<dim3(256), dim3(256), 0, stream>>>(
        seqs, W_ih, W_hh, b_ih, b_hh, W_fc, b_fc, out, hbuf, flags);
}

// Round 8
// 1542.917 us; speedup vs baseline: 1.1925x; 1.0150x over previous
//
#include <hip/hip_runtime.h>
#include <hip/hip_bf16.h>
#include <stdint.h>

#define T_STEPS 512
#define BATCH   128
#define IN      512
#define HID     1024
#define OUTN    256

typedef __bf16 bf16x8 __attribute__((ext_vector_type(8)));
typedef float  f32x4  __attribute__((ext_vector_type(4)));
typedef unsigned short us8 __attribute__((ext_vector_type(8)));
typedef unsigned int   ui4 __attribute__((ext_vector_type(4)));

__device__ __forceinline__ unsigned short f2bf(float f) {
    uint32_t u = __float_as_uint(f);
    uint32_t r = (u + 0x7fffu + ((u >> 16) & 1u)) >> 16;   // RNE
    return (unsigned short)r;
}

// Agent-coherent 16B load (bypass L1+L2, read at LLC). Issue-only; completion
// claimed by explicit s_waitcnt.
__device__ __forceinline__ ui4 ld_u128_agent(const void* p) {
    ui4 v;
    asm volatile("global_load_dwordx4 %0, %1, off sc0 sc1"
                 : "=v"(v) : "v"(p) : "memory");
    return v;
}

// Swizzled LDS fragment load: 16B at row*stride + (kbyte ^ ((row&7)<<4))
__device__ __forceinline__ bf16x8 ld_frag(const unsigned short* smem, int row, int kbyte, int rowstride) {
    int off = row * rowstride + (kbyte ^ ((row & 7) << 4));
    return *reinterpret_cast<const bf16x8*>(reinterpret_cast<const char*>(smem) + off);
}

__global__ __launch_bounds__(256, 1) void rnn_persistent(
    const float* __restrict__ seqs, const float* __restrict__ W_ih,
    const float* __restrict__ W_hh, const float* __restrict__ b_ih,
    const float* __restrict__ b_hh, const float* __restrict__ W_fc,
    const float* __restrict__ b_fc, float* __restrict__ out,
    unsigned short* __restrict__ hbuf,   // [2][128][1024] bf16 ring (untagged)
    float* __restrict__ hfinal,          // [128][1024] fp32
    unsigned int* __restrict__ flags)    // [8][32][16] padded: one 64B line per flag, zeroed
{
    const int tid  = threadIdx.x;
    const int lane = tid & 63;
    const int wv   = tid >> 6;          // wave 0..3 (K-split)
    const int wg   = blockIdx.x;
    const int g    = wg >> 5;           // batch group 0..7 (rows g*16..+15)
    const int w    = wg & 31;           // col slice (cols w*32..+31)
    const int gr0  = g * 16;
    const int c0   = w * 32;
    const int ln15 = lane & 15;
    const int lk   = lane >> 4;

    __shared__ unsigned short xtile[16 * 512];   // 16KB, swizzled bf16
    __shared__ float red[4][16][33];             // wave partials (+1 pad)
    __shared__ float biasS[32];

    // ---- init: weight B-fragments into registers (bf16) ----
    bf16x8 wih[2][4];
    bf16x8 whh[2][8];
    #pragma unroll
    for (int nt = 0; nt < 2; nt++) {
        const int j = c0 + nt * 16 + ln15;
        #pragma unroll
        for (int s = 0; s < 4; s++) {
            const int k = wv * 128 + s * 32 + lk * 8;
            const float* p = W_ih + j * IN + k;
            us8 u;
            #pragma unroll
            for (int e = 0; e < 8; e++) u[e] = f2bf(p[e]);
            wih[nt][s] = __builtin_bit_cast(bf16x8, u);
        }
        #pragma unroll
        for (int s = 0; s < 8; s++) {
            const int k = wv * 256 + s * 32 + lk * 8;
            const float* p = W_hh + j * HID + k;
            us8 u;
            #pragma unroll
            for (int e = 0; e < 8; e++) u[e] = f2bf(p[e]);
            whh[nt][s] = __builtin_bit_cast(bf16x8, u);
        }
    }
    if (tid < 32) biasS[tid] = b_ih[c0 + tid] + b_hh[c0 + tid];

    unsigned int* grp_flags = flags + g * 32 * 16;   // 64B-padded flags
    unsigned int* my_flag   = grp_flags + w * 16;

    // per-lane direct A-frag byte offset into the group's h block:
    // row = lane&15 (2048B rows), k-slot = (lane>>4)*16B, wave K-base = wv*512B
    const int hfrag = ln15 * 2048 + wv * 512 + lk * 16;

    // per-thread x chunk coords (16B chunks, 64 per row)
    const int xrow[4] = { (tid) >> 6, (tid + 256) >> 6, (tid + 512) >> 6, (tid + 768) >> 6 };
    const int xcol[4] = { (tid) & 63, (tid + 256) & 63, (tid + 512) & 63, (tid + 768) & 63 };

    // ---- prologue: load + convert x(0) ----
    us8 xbf[4];
    {
        const float* xsrc = seqs + (size_t)gr0 * IN;
        #pragma unroll
        for (int it = 0; it < 4; it++) {
            const float* s4 = xsrc + xrow[it] * IN + xcol[it] * 8;
            float4 a = *reinterpret_cast<const float4*>(s4);
            float4 b = *reinterpret_cast<const float4*>(s4 + 4);
            us8 u;
            u[0]=f2bf(a.x); u[1]=f2bf(a.y); u[2]=f2bf(a.z); u[3]=f2bf(a.w);
            u[4]=f2bf(b.x); u[5]=f2bf(b.y); u[6]=f2bf(b.z); u[7]=f2bf(b.w);
            xbf[it] = u;
        }
    }

    const size_t slotB = (size_t)BATCH * HID * 2;   // 256KB per ring slot
    char* hbase = reinterpret_cast<char*>(hbuf);

    for (int t = 0; t < T_STEPS; t++) {
        // 1: write prepared x(t) -> xtile (swizzled)
        #pragma unroll
        for (int it = 0; it < 4; it++) {
            const int off = xrow[it] * 1024 + ((xcol[it] * 16) ^ ((xrow[it] & 7) << 4));
            *reinterpret_cast<us8*>(reinterpret_cast<char*>(xtile) + off) = xbf[it];
        }

        // 2: issue x(t+1) plain loads (HBM latency hides under the spin)
        float4 xr[8];
        {
            const int tn = (t + 1 < T_STEPS) ? t + 1 : t;
            const float* xsrc = seqs + (size_t)tn * (BATCH * IN) + (size_t)gr0 * IN;
            #pragma unroll
            for (int it = 0; it < 4; it++) {
                const float* s4 = xsrc + xrow[it] * IN + xcol[it] * 8;
                xr[2*it]   = *reinterpret_cast<const float4*>(s4);
                xr[2*it+1] = *reinterpret_cast<const float4*>(s4 + 4);
            }
        }

        // 3: flag spin (wave0, 32 lanes, one 64B line per flag)
        if (t > 0 && wv == 0 && lane < 32) {
            const unsigned int* f = grp_flags + lane * 16;
            while (__hip_atomic_load(f, __ATOMIC_RELAXED, __HIP_MEMORY_SCOPE_AGENT) < (unsigned)t) {
                __builtin_amdgcn_s_sleep(1);
            }
        }
        __syncthreads();   // B1: xtile visible; h(t) certified at LLC (writers drained)

        // 4: issue 8 direct A-frag h-loads (LLC -> registers, no LDS staging)
        ui4 hv[8];
        if (t > 0) {
            const char* hsrc = hbase + (size_t)(t & 1) * slotB + (size_t)gr0 * 2048 + hfrag;
            #pragma unroll
            for (int s = 0; s < 8; s++) hv[s] = ld_u128_agent(hsrc + s * 64);
        }
        __builtin_amdgcn_sched_barrier(0);

        // 5: x-projection MFMAs (overlap h-load round trip)
        f32x4 acc0 = {0.f, 0.f, 0.f, 0.f};
        f32x4 acc1 = {0.f, 0.f, 0.f, 0.f};
        {
            const int kx0b = wv * 256;
            #pragma unroll
            for (int s = 0; s < 4; s++) {
                bf16x8 a = ld_frag(xtile, ln15, kx0b + s * 64 + lk * 16, 1024);
                acc0 = __builtin_amdgcn_mfma_f32_16x16x32_bf16(a, wih[0][s], acc0, 0, 0, 0);
                acc1 = __builtin_amdgcn_mfma_f32_16x16x32_bf16(a, wih[1][s], acc1, 0, 0, 0);
            }
        }

        if (t > 0) {
            // 6: claim h A-frags, feed MFMA directly from registers
            asm volatile("s_waitcnt vmcnt(0)" ::: "memory");
            __builtin_amdgcn_sched_barrier(0);
            #pragma unroll
            for (int s = 0; s < 8; s++) {
                bf16x8 a = __builtin_bit_cast(bf16x8, hv[s]);
                acc0 = __builtin_amdgcn_mfma_f32_16x16x32_bf16(a, whh[0][s], acc0, 0, 0, 0);
                acc1 = __builtin_amdgcn_mfma_f32_16x16x32_bf16(a, whh[1][s], acc1, 0, 0, 0);
            }
        }

        // 7: cross-wave K-reduction partials
        #pragma unroll
        for (int r = 0; r < 4; r++) {
            red[wv][lk * 4 + r][ln15]      = acc0[r];
            red[wv][lk * 4 + r][16 + ln15] = acc1[r];
        }
        __syncthreads();   // B2

        // 8: reduce + bias + relu
        const int hrow = tid >> 4;          // 0..15
        const int co2  = (tid & 15) * 2;    // even col within slice
        float v0 = red[0][hrow][co2]   + red[1][hrow][co2]   + red[2][hrow][co2]   + red[3][hrow][co2]   + biasS[co2];
        float v1 = red[0][hrow][co2+1] + red[1][hrow][co2+1] + red[2][hrow][co2+1] + red[3][hrow][co2+1] + biasS[co2+1];
        v0 = fmaxf(v0, 0.0f);
        v1 = fmaxf(v1, 0.0f);

        // 9: store H_{t+1} (bf16 ring; fp32 hfinal at last step)
        if (t < T_STEPS - 1) {
            unsigned pack = (unsigned)f2bf(v0) | ((unsigned)f2bf(v1) << 16);
            unsigned* dst = reinterpret_cast<unsigned*>(
                hbase + (size_t)((t + 1) & 1) * slotB
                + ((size_t)(gr0 + hrow) * HID + c0 + co2) * 2);
            __hip_atomic_store(dst, pack, __ATOMIC_RELAXED, __HIP_MEMORY_SCOPE_AGENT);
        } else {
            unsigned long long pack = ((unsigned long long)__float_as_uint(v1) << 32) | __float_as_uint(v0);
            unsigned long long* dst = reinterpret_cast<unsigned long long*>(
                hfinal + (size_t)(gr0 + hrow) * HID + c0 + co2);
            __hip_atomic_store(dst, pack, __ATOMIC_RELAXED, __HIP_MEMORY_SCOPE_AGENT);
        }

        // 10: drain (certify h at LLC; also claims x loads) -> barrier -> flag
        asm volatile("s_waitcnt vmcnt(0)" ::: "memory");
        __builtin_amdgcn_sched_barrier(0);
        __syncthreads();   // B3: every thread's store drained
        if (tid == 0) {
            __hip_atomic_store(my_flag, (unsigned)(t + 1), __ATOMIC_RELAXED, __HIP_MEMORY_SCOPE_AGENT);
        }

        // 11: convert x(t+1) — off the signal path (loads already claimed)
        #pragma unroll
        for (int it = 0; it < 4; it++) {
            float4 a = xr[2*it], b = xr[2*it+1];
            us8 u;
            u[0]=f2bf(a.x); u[1]=f2bf(a.y); u[2]=f2bf(a.z); u[3]=f2bf(a.w);
            u[4]=f2bf(b.x); u[5]=f2bf(b.y); u[6]=f2bf(b.z); u[7]=f2bf(b.w);
            xbf[it] = u;
        }
    }

    // ---- final group barrier, then fused FC: out = hfinal @ W_fc^T + b_fc ----
    if (wv == 0 && lane < 32) {
        const unsigned int* f = grp_flags + lane * 16;
        while (__hip_atomic_load(f, __ATOMIC_RELAXED, __HIP_MEMORY_SCOPE_AGENT) < (unsigned)T_STEPS) {
            __builtin_amdgcn_s_sleep(1);
        }
    }
    __syncthreads();
    __threadfence();   // acquire: plain loads below see peers' hfinal

    {
        // WG computes out[gr0..gr0+15][w*8..w*8+7]; 2-way K-split over 256 threads
        const int oi   = tid & 127;
        const int half = tid >> 7;
        const int brow = gr0 + (oi >> 3);
        const int o    = w * 8 + (oi & 7);
        const float* hv2 = hfinal + (size_t)brow * HID + half * 512;
        const float* wf  = W_fc  + (size_t)o * HID + half * 512;
        float sum = 0.f;
        #pragma unroll 4
        for (int k = 0; k < 512; k += 4) {
            float4 hh = *reinterpret_cast<const float4*>(hv2 + k);
            float4 ww = *reinterpret_cast<const float4*>(wf + k);
            sum += hh.x * ww.x + hh.y * ww.y + hh.z * ww.z + hh.w * ww.w;
        }
        float* redf = &red[0][0][0];
        redf[tid] = sum;
        __syncthreads();
        if (tid < 128) {
            out[(size_t)brow * OUTN + o] = redf[tid] + redf[tid + 128] + b_fc[o];
        }
    }
}

extern "C" void kernel_launch(void* const* d_in, const int* in_sizes, int n_in,
                              void* d_out, int out_size, void* d_ws, size_t ws_size,
                              hipStream_t stream) {
    const float* seqs = (const float*)d_in[0];
    const float* W_ih = (const float*)d_in[1];
    const float* W_hh = (const float*)d_in[2];
    const float* b_ih = (const float*)d_in[3];
    const float* b_hh = (const float*)d_in[4];
    const float* W_fc = (const float*)d_in[5];
    const float* b_fc = (const float*)d_in[6];
    float* out = (float*)d_out;

    char* ws = (char*)d_ws;
    unsigned short* hbuf   = (unsigned short*)ws;                 // 2*128*1024*2 = 524288 B
    float*          hfinal = (float*)(ws + 524288);               // 128*1024*4   = 524288 B
    unsigned int*   flags  = (unsigned int*)(ws + 1048576);       // 8*32*64      = 16384 B

    hipMemsetAsync(flags, 0, 8 * 32 * 64, stream);
    rnn_persistent<<<dim3(256), dim3(256), 0, stream>>>(
        seqs, W_ih, W_hh, b_ih, b_hh, W_fc, b_fc, out, hbuf, hfinal, flags);
}